// Round 1
// 246.538 us; speedup vs baseline: 1.0113x; 1.0113x over previous
//
#include <hip/hip_runtime.h>
#include <math.h>

#define NLAB 8
#define BATCH 16
// acc layout per batch (floats):
//   [0..27]  emb sums, labels 1..7 x 4 ch
//   [28..34] cnt_k, labels 1..7
//   [35..40] cnt_i, labels 2..7
//   [41..46] agg sums, labels 2..7
#define S_OFF  0
#define CK_OFF 28
#define CI_OFF 35
#define AG_OFF 41
#define ACC_PER_B 48
#define ACC_FLOATS (BATCH * ACC_PER_B)
#define LAB_OFFSET 4096              // label byte-cache starts here in d_ws
#define GRIDX 200                    // T=51200 threads/batch; P=409600 = 8*T exactly

__device__ __forceinline__ float wave_reduce(float v) {
#pragma unroll
  for (int off = 32; off > 0; off >>= 1) v += __shfl_xor(v, off, 64);
  return v;
}

// ---------------------------------------------------------------------------
// Pass 1: per-batch segment sums.
// R2 layout change: 4 PIXEL-STRIDED slots per thread (p, p+T, p+2T, p+3T)
// instead of 4 consecutive pixels. Every emb float4 load is now
// lane-contiguous (16 cache lines/wave-instr instead of 64); inst/ker/tmk
// become scalar dword loads (4 lines/instr, still fully coalesced).
// Wave-iter line-requests: 304 -> 112; in-flight loads/thread: 7 -> 16.
// Label cache is 1 byte/pixel (coalesced byte stores/loads).
// ---------------------------------------------------------------------------
__global__ __launch_bounds__(256, 4) void k_accum(
    const float4* __restrict__ emb, const int* __restrict__ inst,
    const float* __restrict__ ker, const float* __restrict__ tmk,
    float* __restrict__ acc, unsigned char* __restrict__ labc,
    int P, int use_cache)
{
  const int b = blockIdx.y;
  const size_t base = (size_t)b * P;
  const float4* e  = emb + base;
  const int*    ip = inst + base;
  const float*  kp = ker + base;
  const float*  tp = tmk + base;
  unsigned char* lb = labc + base;

  float s[7][4], ck[7], ci[6];
#pragma unroll
  for (int l = 0; l < 7; ++l) {
    ck[l] = 0.f;
    s[l][0] = 0.f; s[l][1] = 0.f; s[l][2] = 0.f; s[l][3] = 0.f;
  }
#pragma unroll
  for (int l = 0; l < 6; ++l) ci[l] = 0.f;

  const int T   = blockDim.x * gridDim.x;
  const int tid = blockIdx.x * blockDim.x + threadIdx.x;

  for (int p0 = tid; p0 < P; p0 += 4 * T) {
    const int p1 = p0 + T, p2 = p0 + 2 * T, p3 = p0 + 3 * T;
    const bool v1 = p1 < P, v2 = p2 < P, v3 = p3 < P;
    const int q1 = v1 ? p1 : p0, q2 = v2 ? p2 : p0, q3 = v3 ? p3 : p0;

    // issue all 16 loads up front; each is lane-contiguous
    int   i0 = ip[p0], i1 = ip[q1], i2 = ip[q2], i3 = ip[q3];
    float t0v = tp[p0], t1v = tp[q1], t2v = tp[q2], t3v = tp[q3];
    float c0v = kp[p0], c1v = kp[q1], c2v = kp[q2], c3v = kp[q3];
    float4 e0 = e[p0], e1 = e[q1], e2 = e[q2], e3 = e[q3];

    int lab0 = (t0v > 0.5f)       ? (i0 & 7) : 0;
    int lab1 = (v1 && t1v > 0.5f) ? (i1 & 7) : 0;
    int lab2 = (v2 && t2v > 0.5f) ? (i2 & 7) : 0;
    int lab3 = (v3 && t3v > 0.5f) ? (i3 & 7) : 0;
    float k0 = (c0v > 0.5f) ? 1.f : 0.f;
    float k1 = (c1v > 0.5f) ? 1.f : 0.f;
    float k2 = (c2v > 0.5f) ? 1.f : 0.f;
    float k3 = (c3v > 0.5f) ? 1.f : 0.f;

    if (use_cache) {
      lb[p0] = (unsigned char)lab0;
      if (v1) lb[p1] = (unsigned char)lab1;
      if (v2) lb[p2] = (unsigned char)lab2;
      if (v3) lb[p3] = (unsigned char)lab3;
    }

#pragma unroll
    for (int l = 1; l < NLAB; ++l) {
      float m0 = (lab0 == l) ? 1.f : 0.f;
      float m1 = (lab1 == l) ? 1.f : 0.f;
      float m2 = (lab2 == l) ? 1.f : 0.f;
      float m3 = (lab3 == l) ? 1.f : 0.f;
      float mk0 = m0 * k0, mk1 = m1 * k1, mk2 = m2 * k2, mk3 = m3 * k3;
      ck[l - 1] += (mk0 + mk1) + (mk2 + mk3);
      s[l - 1][0] = fmaf(mk0, e0.x, fmaf(mk1, e1.x, fmaf(mk2, e2.x, fmaf(mk3, e3.x, s[l - 1][0]))));
      s[l - 1][1] = fmaf(mk0, e0.y, fmaf(mk1, e1.y, fmaf(mk2, e2.y, fmaf(mk3, e3.y, s[l - 1][1]))));
      s[l - 1][2] = fmaf(mk0, e0.z, fmaf(mk1, e1.z, fmaf(mk2, e2.z, fmaf(mk3, e3.z, s[l - 1][2]))));
      s[l - 1][3] = fmaf(mk0, e0.w, fmaf(mk1, e1.w, fmaf(mk2, e2.w, fmaf(mk3, e3.w, s[l - 1][3]))));
      if (l >= 2) ci[l - 2] += (m0 + m1) + (m2 + m3);
    }
  }

  // block-level reduction: wave_reduce -> LDS -> one atomic per block per slot
  __shared__ float red[4][48];
  const int wid = threadIdx.x >> 6, lane = threadIdx.x & 63;
#pragma unroll
  for (int l = 0; l < 7; ++l) {
#pragma unroll
    for (int c = 0; c < 4; ++c) {
      float v = wave_reduce(s[l][c]);
      if (lane == 0) red[wid][S_OFF + l * 4 + c] = v;
    }
    float vk = wave_reduce(ck[l]);
    if (lane == 0) red[wid][CK_OFF + l] = vk;
  }
#pragma unroll
  for (int l = 0; l < 6; ++l) {
    float vi = wave_reduce(ci[l]);
    if (lane == 0) red[wid][CI_OFF + l] = vi;
  }
  __syncthreads();
  if (threadIdx.x < AG_OFF) {
    float v = red[0][threadIdx.x] + red[1][threadIdx.x] +
              red[2][threadIdx.x] + red[3][threadIdx.x];
    atomicAdd(acc + b * ACC_PER_B + threadIdx.x, v);
  }
}

// ---------------------------------------------------------------------------
// Pass 2: aggregation term vs mu, labels 2..7 only. emb should be L3-resident
// after pass 1. Same pixel-strided slot layout as pass 1.
// ---------------------------------------------------------------------------
__global__ __launch_bounds__(256, 4) void k_agg(
    const float4* __restrict__ emb, const int* __restrict__ inst,
    const float* __restrict__ tmk, const unsigned char* __restrict__ labc,
    float* __restrict__ acc, int P, int use_cache)
{
  const int b = blockIdx.y;
  const size_t base = (size_t)b * P;
  __shared__ float4 smu[NLAB];
  const float* accB = acc + b * ACC_PER_B;
  if (threadIdx.x < NLAB) {
    int l = threadIdx.x;
    float4 m;
    if (l == 0) {
      m = make_float4(0.f, 0.f, 0.f, 0.f);
    } else {
      float inv = 1.f / fmaxf(accB[CK_OFF + l - 1], 1.f);
      m = make_float4(accB[S_OFF + (l - 1) * 4 + 0] * inv,
                      accB[S_OFF + (l - 1) * 4 + 1] * inv,
                      accB[S_OFF + (l - 1) * 4 + 2] * inv,
                      accB[S_OFF + (l - 1) * 4 + 3] * inv);
    }
    smu[l] = m;
  }
  __syncthreads();

  const float4* e = emb + base;
  const unsigned char* lb = labc + base;
  const int*   ip = inst + base;
  const float* tp = tmk + base;

  float aggl[6];
#pragma unroll
  for (int l = 0; l < 6; ++l) aggl[l] = 0.f;

  const int T   = blockDim.x * gridDim.x;
  const int tid = blockIdx.x * blockDim.x + threadIdx.x;

  for (int p0 = tid; p0 < P; p0 += 4 * T) {
    const int p1 = p0 + T, p2 = p0 + 2 * T, p3 = p0 + 3 * T;
    const bool v1 = p1 < P, v2 = p2 < P, v3 = p3 < P;
    const int q1 = v1 ? p1 : p0, q2 = v2 ? p2 : p0, q3 = v3 ? p3 : p0;

    int lab0, lab1, lab2, lab3;
    if (use_cache) {
      lab0 = lb[p0];
      lab1 = v1 ? lb[p1] : 0;
      lab2 = v2 ? lb[p2] : 0;
      lab3 = v3 ? lb[p3] : 0;
    } else {
      int   i0 = ip[p0], i1 = ip[q1], i2 = ip[q2], i3 = ip[q3];
      float t0v = tp[p0], t1v = tp[q1], t2v = tp[q2], t3v = tp[q3];
      lab0 = (t0v > 0.5f)       ? (i0 & 7) : 0;
      lab1 = (v1 && t1v > 0.5f) ? (i1 & 7) : 0;
      lab2 = (v2 && t2v > 0.5f) ? (i2 & 7) : 0;
      lab3 = (v3 && t3v > 0.5f) ? (i3 & 7) : 0;
    }
    float4 e0 = e[p0], e1 = e[q1], e2 = e[q2], e3 = e[q3];

#pragma unroll
    for (int i = 0; i < 4; ++i) {
      int lab = (i == 0) ? lab0 : (i == 1) ? lab1 : (i == 2) ? lab2 : lab3;
      float4 ev = (i == 0) ? e0 : (i == 1) ? e1 : (i == 2) ? e2 : e3;
      float4 mv = smu[lab];
      float dx = ev.x - mv.x, dy = ev.y - mv.y;
      float dz = ev.z - mv.z, dw = ev.w - mv.w;
      float sq = dx * dx + dy * dy + dz * dz + dw * dw;
      float d = sqrtf(sq);
      float t = fmaxf(d - 0.5f, 0.f);                  // DELTA_V
      float term = (lab >= 2) ? logf(fmaf(t, t, 1.f)) : 0.f;
#pragma unroll
      for (int l = 0; l < 6; ++l) aggl[l] += (lab == l + 2) ? term : 0.f;
    }
  }

  __shared__ float red[4][8];
  const int wid = threadIdx.x >> 6, lane = threadIdx.x & 63;
#pragma unroll
  for (int l = 0; l < 6; ++l) {
    float v = wave_reduce(aggl[l]);
    if (lane == 0) red[wid][l] = v;
  }
  __syncthreads();
  if (threadIdx.x < 6) {
    float v = red[0][threadIdx.x] + red[1][threadIdx.x] +
              red[2][threadIdx.x] + red[3][threadIdx.x];
    atomicAdd(acc + b * ACC_PER_B + AG_OFF + threadIdx.x, v);
  }
}

// ---------------------------------------------------------------------------
// Finalize: one wave; lane b handles batch b, then wave-reduce the batch mean.
// ---------------------------------------------------------------------------
__global__ void k_final(const float* __restrict__ acc, float* __restrict__ out, int nb) {
  const int lane = threadIdx.x;
  float loss = 0.f;
  if (lane < nb) {
    const float* a = acc + lane * ACC_PER_B;
    float mu[NLAB][4];
#pragma unroll
    for (int c = 0; c < 4; ++c) mu[0][c] = 0.f;
#pragma unroll
    for (int l = 1; l < NLAB; ++l) {
      float inv = 1.f / fmaxf(a[CK_OFF + l - 1], 1.f);
#pragma unroll
      for (int c = 0; c < 4; ++c) mu[l][c] = a[S_OFF + (l - 1) * 4 + c] * inv;
    }
    // l_agg = mean over labels 2..7 of agg_sum / max(cnt_i,1)
    float l_agg = 0.f;
#pragma unroll
    for (int l = 2; l < NLAB; ++l)
      l_agg += a[AG_OFF + l - 2] / fmaxf(a[CI_OFF + l - 2], 1.f);
    l_agg *= (1.f / 6.f);
    // l_dis over ordered pairs i!=j, i,j in 1..7 (42 pairs)
    float ssum = 0.f;
    for (int i = 1; i < NLAB; ++i)
      for (int j = 1; j < NLAB; ++j) {
        if (i == j) continue;
        float dx = mu[i][0] - mu[j][0], dy = mu[i][1] - mu[j][1];
        float dz = mu[i][2] - mu[j][2], dw = mu[i][3] - mu[j][3];
        float dd = sqrtf(dx * dx + dy * dy + dz * dz + dw * dw);
        float t = fmaxf(3.0f - dd, 0.f);         // 2*DELTA_D
        ssum += logf(fmaf(t, t, 1.f));
      }
    float l_dis = ssum / 42.f;
    // l_reg: mu[0]=0 contributes log(1)=0; mean over all 8 labels
    float rsum = 0.f;
#pragma unroll
    for (int l = 1; l < NLAB; ++l) {
      float n = sqrtf(mu[l][0] * mu[l][0] + mu[l][1] * mu[l][1] +
                      mu[l][2] * mu[l][2] + mu[l][3] * mu[l][3]);
      rsum += logf(n + 1.f);
    }
    float l_reg = rsum * (0.001f / NLAB);
    loss = l_agg + l_dis + l_reg;
  }
  loss = wave_reduce(loss);
  if (lane == 0) out[0] = loss / (float)nb;      // LOSS_WEIGHT = 1
}

extern "C" void kernel_launch(void* const* d_in, const int* in_sizes, int n_in,
                              void* d_out, int out_size, void* d_ws, size_t ws_size,
                              hipStream_t stream) {
  const float4* emb = (const float4*)d_in[0];
  const int*    inst = (const int*)d_in[1];
  const float*  ker  = (const float*)d_in[2];
  const float*  tmk  = (const float*)d_in[3];
  float* out = (float*)d_out;

  const int total = in_sizes[1];       // B*H*W
  const int P = total / BATCH;

  float* acc = (float*)d_ws;
  unsigned char* labc = (unsigned char*)((char*)d_ws + LAB_OFFSET);
  const size_t need = (size_t)LAB_OFFSET + (size_t)total;   // 1 byte per pixel
  const int use_cache = (ws_size >= need) ? 1 : 0;

  // d_ws is re-poisoned to 0xAA before every launch — zero the accumulators.
  hipMemsetAsync(d_ws, 0, ACC_FLOATS * sizeof(float), stream);

  dim3 grid(GRIDX, BATCH);             // 3200 blocks
  k_accum<<<grid, 256, 0, stream>>>(emb, inst, ker, tmk, acc, labc, P, use_cache);
  k_agg  <<<grid, 256, 0, stream>>>(emb, inst, tmk, labc, acc, P, use_cache);
  k_final<<<1, 64, 0, stream>>>(acc, out, BATCH);
}